// Round 2
// baseline (33067.258 us; speedup 1.0000x reference)
//
#include <hip/hip_runtime.h>

#define HDIM 512
#define BATCH 256
#define NSEQ 144

__device__ __forceinline__ float fast_sigmoid(float x) {
    return 1.0f / (1.0f + __expf(-x));
}
__device__ __forceinline__ float fast_tanh(float x) {
    x = fminf(fmaxf(x, -12.0f), 12.0f);
    float e = __expf(2.0f * x);
    return (e - 1.0f) / (e + 1.0f);
}

__device__ __forceinline__ void dot4(float& acc, const float4& a, const float4& b) {
    acc = fmaf(a.x, b.x, acc);
    acc = fmaf(a.y, b.y, acc);
    acc = fmaf(a.z, b.z, acc);
    acc = fmaf(a.w, b.w, acc);
}

// One LSTM time step, fused: gates GEMM + cell update + (optional) head partial.
// grid = 256 blocks: blockIdx >> 5 = batch tile (32 rows), blockIdx & 31 = j tile (16 cols).
// Each thread: 2 batch rows x 1 hidden col x 4 gates.
template<int I, bool HEAD>
__global__ __launch_bounds__(256)
void lstm_step_kernel(const float* __restrict__ x, int T, int t,
                      const float* __restrict__ Wih,   // [4H][I]
                      const float* __restrict__ Whh,   // [4H][H]
                      const float* __restrict__ bih,   // [4H]
                      const float* __restrict__ bhh,   // [4H]
                      const float* __restrict__ h_in,  // [B][H]
                      float* __restrict__ h_out,       // [B][H]
                      float* __restrict__ c,           // [B][H] in/out
                      const float* __restrict__ headW, // [H]
                      float* __restrict__ partials,    // [B][144][32]
                      int seq_t)
{
    __shared__ float xs[32][I + 4];       // +4 pad: rows 4 banks apart
    __shared__ float hs[32][HDIM + 4];

    const int tid = threadIdx.x;
    const int bt = blockIdx.x >> 5;       // 0..7
    const int jt = blockIdx.x & 31;       // 0..31
    const int b_base = bt * 32;

    // stage x[b_base..+32, t, :I]
    for (int idx = tid; idx < 32 * (I / 4); idx += 256) {
        int row = idx / (I / 4);
        int col = (idx % (I / 4)) * 4;
        float4 v = *reinterpret_cast<const float4*>(x + ((size_t)(b_base + row) * T + t) * I + col);
        *reinterpret_cast<float4*>(&xs[row][col]) = v;
    }
    // stage h_in[b_base..+32, :]
    for (int idx = tid; idx < 32 * (HDIM / 4); idx += 256) {
        int row = idx >> 7;
        int col = (idx & 127) << 2;
        float4 v = *reinterpret_cast<const float4*>(h_in + (size_t)(b_base + row) * HDIM + col);
        *reinterpret_cast<float4*>(&hs[row][col]) = v;
    }
    __syncthreads();

    const int j_s = tid & 15;             // hidden col within tile
    const int b_l = tid >> 4;             // 0..15 (handles b_l and b_l+16)
    const int j = jt * 16 + j_s;

    float acc0[4], acc1[4];
#pragma unroll
    for (int g = 0; g < 4; ++g) {
        float bsum = bih[g * HDIM + j] + bhh[g * HDIM + j];
        acc0[g] = bsum;
        acc1[g] = bsum;
    }

    // x @ Wih^T part (K = I)
    {
        const float* wr0 = Wih + (size_t)(0 * HDIM + j) * I;
        const float* wr1 = Wih + (size_t)(1 * HDIM + j) * I;
        const float* wr2 = Wih + (size_t)(2 * HDIM + j) * I;
        const float* wr3 = Wih + (size_t)(3 * HDIM + j) * I;
#pragma unroll 2
        for (int k = 0; k < I; k += 4) {
            float4 w0 = *reinterpret_cast<const float4*>(wr0 + k);
            float4 w1 = *reinterpret_cast<const float4*>(wr1 + k);
            float4 w2 = *reinterpret_cast<const float4*>(wr2 + k);
            float4 w3 = *reinterpret_cast<const float4*>(wr3 + k);
            float4 z0 = *reinterpret_cast<const float4*>(&xs[b_l][k]);
            float4 z1 = *reinterpret_cast<const float4*>(&xs[b_l + 16][k]);
            dot4(acc0[0], z0, w0); dot4(acc0[1], z0, w1);
            dot4(acc0[2], z0, w2); dot4(acc0[3], z0, w3);
            dot4(acc1[0], z1, w0); dot4(acc1[1], z1, w1);
            dot4(acc1[2], z1, w2); dot4(acc1[3], z1, w3);
        }
    }
    // h @ Whh^T part (K = 512)
    {
        const float* wr0 = Whh + (size_t)(0 * HDIM + j) * HDIM;
        const float* wr1 = Whh + (size_t)(1 * HDIM + j) * HDIM;
        const float* wr2 = Whh + (size_t)(2 * HDIM + j) * HDIM;
        const float* wr3 = Whh + (size_t)(3 * HDIM + j) * HDIM;
#pragma unroll 2
        for (int k = 0; k < HDIM; k += 4) {
            float4 w0 = *reinterpret_cast<const float4*>(wr0 + k);
            float4 w1 = *reinterpret_cast<const float4*>(wr1 + k);
            float4 w2 = *reinterpret_cast<const float4*>(wr2 + k);
            float4 w3 = *reinterpret_cast<const float4*>(wr3 + k);
            float4 z0 = *reinterpret_cast<const float4*>(&hs[b_l][k]);
            float4 z1 = *reinterpret_cast<const float4*>(&hs[b_l + 16][k]);
            dot4(acc0[0], z0, w0); dot4(acc0[1], z0, w1);
            dot4(acc0[2], z0, w2); dot4(acc0[3], z0, w3);
            dot4(acc1[0], z1, w0); dot4(acc1[1], z1, w1);
            dot4(acc1[2], z1, w2); dot4(acc1[3], z1, w3);
        }
    }

    auto cell = [&](const float* acc, int b) {
        float ig = fast_sigmoid(acc[0]);
        float fg = fast_sigmoid(acc[1]);
        float gg = fast_tanh(acc[2]);
        float og = fast_sigmoid(acc[3]);
        size_t off = (size_t)b * HDIM + j;
        float cn = fmaf(fg, c[off], ig * gg);
        c[off] = cn;
        float hn = og * fast_tanh(cn);
        h_out[off] = hn;
        if (HEAD) {
            float p = hn * headW[j];
#pragma unroll
            for (int m = 8; m >= 1; m >>= 1)
                p += __shfl_xor(p, m, 16);
            if (j_s == 0)
                partials[((size_t)b * NSEQ + seq_t) * 32 + jt] = p;
        }
    };
    cell(acc0, b_base + b_l);
    cell(acc1, b_base + b_l + 16);
}

__global__ __launch_bounds__(256)
void head_finish_kernel(const float* __restrict__ partials,
                        const float* __restrict__ head_b,
                        float* __restrict__ out)
{
    int idx = blockIdx.x * 256 + threadIdx.x;   // b*144 + t
    if (idx >= BATCH * NSEQ) return;
    const float* p = partials + (size_t)idx * 32;
    float s = head_b[0];
#pragma unroll
    for (int i = 0; i < 32; ++i) s += p[i];
    out[idx] = s;
}

extern "C" void kernel_launch(void* const* d_in, const int* in_sizes, int n_in,
                              void* d_out, int out_size, void* d_ws, size_t ws_size,
                              hipStream_t stream) {
    const float* x_d      = (const float*)d_in[0];
    const float* x_f      = (const float*)d_in[1];
    const float* x_ff     = (const float*)d_in[2];
    const float* enc_Wih  = (const float*)d_in[3];
    const float* enc_Whh  = (const float*)d_in[4];
    const float* enc_bih  = (const float*)d_in[5];
    const float* enc_bhh  = (const float*)d_in[6];
    const float* decf_Wih = (const float*)d_in[7];
    const float* decf_Whh = (const float*)d_in[8];
    const float* decf_bih = (const float*)d_in[9];
    const float* decf_bhh = (const float*)d_in[10];
    const float* decff_Wih = (const float*)d_in[11];
    const float* decff_Whh = (const float*)d_in[12];
    const float* decff_bih = (const float*)d_in[13];
    const float* decff_bhh = (const float*)d_in[14];
    const float* head_W   = (const float*)d_in[15];
    const float* head_b   = (const float*)d_in[16];
    float* out = (float*)d_out;

    float* ws    = (float*)d_ws;
    float* hA    = ws;                    // [B*H] = 131072
    float* cc    = ws + 131072;           // [B*H]
    float* hB    = ws + 262144;           // [B*H]
    float* parts = ws + 393216;           // [B*144*32] = 1179648

    // zero h0 and c0 (hA and cc are adjacent)
    hipMemsetAsync(ws, 0, (size_t)262144 * sizeof(float), stream);

    float* hin = hA;
    float* hout = hB;

    // encoder: T=336, I=64
    for (int t = 0; t < 336; ++t) {
        lstm_step_kernel<64, false><<<dim3(256), dim3(256), 0, stream>>>(
            x_d, 336, t, enc_Wih, enc_Whh, enc_bih, enc_bhh,
            hin, hout, cc, nullptr, nullptr, 0);
        float* tmp = hin; hin = hout; hout = tmp;
    }
    // forecast decoder: T=96, I=32, head rows 0..95
    for (int t = 0; t < 96; ++t) {
        lstm_step_kernel<32, true><<<dim3(256), dim3(256), 0, stream>>>(
            x_f, 96, t, decf_Wih, decf_Whh, decf_bih, decf_bhh,
            hin, hout, cc, head_W, parts, t);
        float* tmp = hin; hin = hout; hout = tmp;
    }
    // future decoder: T=48, I=32, head rows 96..143
    for (int t = 0; t < 48; ++t) {
        lstm_step_kernel<32, true><<<dim3(256), dim3(256), 0, stream>>>(
            x_ff, 48, t, decff_Wih, decff_Whh, decff_bih, decff_bhh,
            hin, hout, cc, head_W, parts, 96 + t);
        float* tmp = hin; hin = hout; hout = tmp;
    }
    // head: out[b,t] = sum(parts) + bias
    head_finish_kernel<<<dim3((BATCH * NSEQ + 255) / 256), dim3(256), 0, stream>>>(
        parts, head_b, out);
}

// Round 4
// 19193.025 us; speedup vs baseline: 1.7229x; 1.7229x over previous
//
#include <hip/hip_runtime.h>
#include <hip/hip_bf16.h>

#define HDIM 512
#define BATCH 256
#define NSEQ 144
#define KREG 576          // padded per-region K (x|h|pad)
#define KTRIP 1728        // 3 regions: Whi*zhi + Whi*zlo + Wlo*zhi
#define CHUNK 64
#define NCHUNK 27         // 1728/64

typedef __attribute__((ext_vector_type(8))) short short8;
typedef __attribute__((ext_vector_type(4))) float f32x4;

__device__ __forceinline__ float fast_sigmoid(float x) { return 1.0f / (1.0f + __expf(-x)); }
__device__ __forceinline__ float fast_tanh(float x) {
    x = fminf(fmaxf(x, -12.0f), 12.0f);
    float e = __expf(2.0f * x);
    return (e - 1.0f) / (e + 1.0f);
}
__device__ __forceinline__ short f2bf(float v) {
    __hip_bfloat16 b = __float2bfloat16(v);
    return *reinterpret_cast<short*>(&b);
}
__device__ __forceinline__ float bf2f(short s) {
    __hip_bfloat16 b = *reinterpret_cast<__hip_bfloat16*>(&s);
    return __bfloat162float(b);
}

// Split fp32 -> (hi, lo) bf16 planes. n4 = n/4.
__global__ __launch_bounds__(256)
void xconv_kernel(const float* __restrict__ src, short* __restrict__ hi,
                  short* __restrict__ lo, int n4)
{
    int i = blockIdx.x * 256 + threadIdx.x;
    if (i >= n4) return;
    float4 v = reinterpret_cast<const float4*>(src)[i];
    float vv[4] = {v.x, v.y, v.z, v.w};
    short oh[4], ol[4];
#pragma unroll
    for (int e = 0; e < 4; ++e) {
        short h = f2bf(vv[e]);
        oh[e] = h;
        ol[e] = f2bf(vv[e] - bf2f(h));
    }
    reinterpret_cast<short4*>(hi)[i] = *reinterpret_cast<const short4*>(oh);
    reinterpret_cast<short4*>(lo)[i] = *reinterpret_cast<const short4*>(ol);
}

// Build permuted split weights: Wcat[j'][KTRIP], j' = 4*u + gate (gate order i,f,g,o).
// W regions: (hi, hi, lo)  <-- pairs with Z regions (hi, lo, hi).
template<int I>
__global__ __launch_bounds__(256)
void wprep_kernel(const float* __restrict__ Wih, const float* __restrict__ Whh,
                  const float* __restrict__ bih, const float* __restrict__ bhh,
                  short* __restrict__ Wcat, float* __restrict__ bc)
{
    const int jp = blockIdx.x;            // 0..2047
    const int u = jp >> 2, g = jp & 3;
    const int srow = g * HDIM + u;
    const int t = threadIdx.x;
    if (t == 255) bc[jp] = bih[srow] + bhh[srow];
    if (t >= KTRIP / 8) return;           // 216 active
    const int kt = t * 8;
    const int region = kt / KREG;
    const int kreg = kt % KREG;
    float v[8];
#pragma unroll
    for (int e = 0; e < 8; ++e) {
        int kr = kreg + e;
        float s;
        if (kr < I)             s = Wih[(size_t)srow * I + kr];
        else if (kr < I + HDIM) s = Whh[(size_t)srow * HDIM + (kr - I)];
        else                    s = 0.0f;
        v[e] = s;
    }
    short o[8];
#pragma unroll
    for (int e = 0; e < 8; ++e) {
        short hi = f2bf(v[e]);
        o[e] = (region == 2) ? f2bf(v[e] - bf2f(hi)) : hi;   // (hi, hi, lo)
    }
    *reinterpret_cast<int4*>(Wcat + (size_t)jp * KTRIP + kt) = *reinterpret_cast<const int4*>(o);
}

// One LSTM step via bf16x3 MFMA. grid = 256: bn = blk&15 (gate tile 128),
// bm = blk>>4 (batch tile 16). XCD = blk%8 = bn%8 -> W slice L2-resident per XCD.
// 256 thr = 4 waves, wave M16xN32.
template<int I, bool HEAD>
__global__ __launch_bounds__(256)
void step_mfma(const short* __restrict__ xhi, const short* __restrict__ xlo,
               int T, int t,
               const short* __restrict__ Wcat, const float* __restrict__ bc,
               const short* __restrict__ hhi_in, const short* __restrict__ hlo_in,
               short* __restrict__ hhi_out, short* __restrict__ hlo_out,
               float* __restrict__ cc,
               const float* __restrict__ headW, float* __restrict__ parts, int seq_t)
{
    __shared__ short Wl[128 * 64];   // [row][64] swizzled: off8 ^= (row&7)<<3
    __shared__ short Zl[16 * 64];

    const int tid = threadIdx.x;
    const int bn = blockIdx.x & 15;
    const int bm = blockIdx.x >> 4;

    int4 wpre[4];
    int4 zpre;

    auto fetchW = [&](int kc) {
#pragma unroll
        for (int j = 0; j < 4; ++j) {
            int p = j * 256 + tid;
            int row = p >> 3;
            int c16 = p & 7;
            wpre[j] = *reinterpret_cast<const int4*>(
                Wcat + (size_t)(bn * 128 + row) * KTRIP + kc * CHUNK + c16 * 8);
        }
    };
    auto fetchZ = [&](int kc) {
        if (tid < 128) {
            int row = tid >> 3;
            int k8 = tid & 7;
            int region = (kc * CHUNK) / KREG;
            int kreg = (kc * CHUNK) % KREG + k8 * 8;
            int b = bm * 16 + row;
            const short* xs = (region == 1) ? xlo : xhi;
            const short* hs = (region == 1) ? hlo_in : hhi_in;
            if (kreg < I) {
                zpre = *reinterpret_cast<const int4*>(xs + ((size_t)b * T + t) * I + kreg);
            } else if (kreg < I + HDIM) {
                zpre = *reinterpret_cast<const int4*>(hs + ((size_t)b << 9) + (kreg - I));
            } else {
                zpre = make_int4(0, 0, 0, 0);
            }
        }
    };
    auto writeLDS = [&]() {
#pragma unroll
        for (int j = 0; j < 4; ++j) {
            int p = j * 256 + tid;
            int row = p >> 3;
            int c16 = p & 7;
            *reinterpret_cast<int4*>(Wl + row * 64 + ((c16 * 8) ^ ((row & 7) << 3))) = wpre[j];
        }
        if (tid < 128) {
            int row = tid >> 3;
            int k8 = tid & 7;
            *reinterpret_cast<int4*>(Zl + row * 64 + ((k8 * 8) ^ ((row & 7) << 3))) = zpre;
        }
    };

    const int w = tid >> 6;
    const int lane = tid & 63;
    const int l15 = lane & 15;
    const int lg = lane >> 4;

    f32x4 acc0 = {0.f, 0.f, 0.f, 0.f};
    f32x4 acc1 = {0.f, 0.f, 0.f, 0.f};

    fetchW(0); fetchZ(0);
    for (int kc = 0; kc < NCHUNK; ++kc) {
        if (kc) __syncthreads();          // prior compute done before overwrite
        writeLDS();
        __syncthreads();                  // LDS visible
        if (kc + 1 < NCHUNK) { fetchW(kc + 1); fetchZ(kc + 1); }  // hide under MFMA
#pragma unroll
        for (int kk = 0; kk < 2; ++kk) {
            int koff = kk * 32 + lg * 8;
            short8 a = *reinterpret_cast<const short8*>(
                Zl + l15 * 64 + (koff ^ ((l15 & 7) << 3)));
            int rb0 = w * 32 + l15;
            short8 b0 = *reinterpret_cast<const short8*>(
                Wl + rb0 * 64 + (koff ^ ((rb0 & 7) << 3)));
            int rb1 = rb0 + 16;
            short8 b1 = *reinterpret_cast<const short8*>(
                Wl + rb1 * 64 + (koff ^ ((rb1 & 7) << 3)));
            acc0 = __builtin_amdgcn_mfma_f32_16x16x32_bf16(a, b0, acc0, 0, 0, 0);
            acc1 = __builtin_amdgcn_mfma_f32_16x16x32_bf16(a, b1, acc1, 0, 0, 0);
        }
    }

    // Epilogue: D row=(lg*4+r)=batch, col=l15 -> jp. Lanes 4u..4u+3 hold i,f,g,o.
    float hp[4] = {0.f, 0.f, 0.f, 0.f};
#pragma unroll
    for (int nt = 0; nt < 2; ++nt) {
        int jp = bn * 128 + w * 32 + nt * 16 + l15;
        float bias = bc[jp];
        int u = jp >> 2;
#pragma unroll
        for (int r = 0; r < 4; ++r) {
            float v = (nt ? acc1[r] : acc0[r]) + bias;
            int gs = lane & 3;
            float a = (gs == 2) ? fast_tanh(v) : fast_sigmoid(v);
            int base = lane & ~3;
            float ai = __shfl(a, base,     64);
            float af = __shfl(a, base | 1, 64);
            float ag = __shfl(a, base | 2, 64);
            float ao = __shfl(a, base | 3, 64);
            int b_ = bm * 16 + lg * 4 + r;
            int off = (b_ << 9) + u;
            float cold = cc[off];
            float cn = af * cold + ai * ag;
            float hn = ao * fast_tanh(cn);
            if (gs == 0) {
                cc[off] = cn;
                short hh = f2bf(hn);
                hhi_out[off] = hh;
                hlo_out[off] = f2bf(hn - bf2f(hh));
            }
            if (HEAD) {
                float p = (gs == 0) ? hn * headW[u] : 0.f;
                p += __shfl_xor(p, 4, 64);
                p += __shfl_xor(p, 8, 64);
                hp[r] += p;
            }
        }
    }
    if (HEAD && l15 == 0) {
        int slot = bn * 4 + w;   // 64 slots of 8 hidden units
#pragma unroll
        for (int r = 0; r < 4; ++r) {
            int b_ = bm * 16 + lg * 4 + r;
            parts[((size_t)b_ * NSEQ + seq_t) * 64 + slot] = hp[r];
        }
    }
}

__global__ __launch_bounds__(256)
void head_finish_kernel(const float* __restrict__ partials,
                        const float* __restrict__ head_b,
                        float* __restrict__ out)
{
    int idx = blockIdx.x * 256 + threadIdx.x;   // b*144 + t
    if (idx >= BATCH * NSEQ) return;
    const float* p = partials + (size_t)idx * 64;
    float s = head_b[0];
#pragma unroll
    for (int i = 0; i < 64; ++i) s += p[i];
    out[idx] = s;
}

extern "C" void kernel_launch(void* const* d_in, const int* in_sizes, int n_in,
                              void* d_out, int out_size, void* d_ws, size_t ws_size,
                              hipStream_t stream) {
    const float* x_d      = (const float*)d_in[0];
    const float* x_f      = (const float*)d_in[1];
    const float* x_ff     = (const float*)d_in[2];
    const float* enc_Wih  = (const float*)d_in[3];
    const float* enc_Whh  = (const float*)d_in[4];
    const float* enc_bih  = (const float*)d_in[5];
    const float* enc_bhh  = (const float*)d_in[6];
    const float* decf_Wih = (const float*)d_in[7];
    const float* decf_Whh = (const float*)d_in[8];
    const float* decf_bih = (const float*)d_in[9];
    const float* decf_bhh = (const float*)d_in[10];
    const float* decff_Wih = (const float*)d_in[11];
    const float* decff_Whh = (const float*)d_in[12];
    const float* decff_bih = (const float*)d_in[13];
    const float* decff_bhh = (const float*)d_in[14];
    const float* head_W   = (const float*)d_in[15];
    const float* head_b   = (const float*)d_in[16];
    float* out = (float*)d_out;

    char* base = (char*)d_ws;
    float* cc   = (float*)(base + 0);            //   524288 B
    short* hAhi = (short*)(base + 524288);       //   262144
    short* hAlo = (short*)(base + 786432);       //   262144
    short* hBhi = (short*)(base + 1048576);      //   262144
    short* hBlo = (short*)(base + 1310720);      //   262144
    float* parts = (float*)(base + 1572864);     //  9437184
    float* bcomb = (float*)(base + 11010048);    //    24576
    short* Wcat  = (short*)(base + 11034624);    // 21233664 (3 x 2048 x 1728 shorts)
    short* xdhi  = (short*)(base + 32268288);    // 11010048
    short* xdlo  = (short*)(base + 43278336);    // 11010048
    short* xfhi  = (short*)(base + 54288384);    //  1572864
    short* xflo  = (short*)(base + 55861248);    //  1572864
    short* xffhi = (short*)(base + 57434112);    //   786432
    short* xfflo = (short*)(base + 58220544);    //   786432
    const size_t WSTRIDE = (size_t)2048 * KTRIP;

    // zero c0 and h0 (cc, hAhi, hAlo contiguous)
    hipMemsetAsync(base, 0, 1048576, stream);

    // input split-precision conversion (once per call)
    xconv_kernel<<<dim3(5376), dim3(256), 0, stream>>>(x_d,  xdhi,  xdlo,  1376256);
    xconv_kernel<<<dim3(768),  dim3(256), 0, stream>>>(x_f,  xfhi,  xflo,  196608);
    xconv_kernel<<<dim3(384),  dim3(256), 0, stream>>>(x_ff, xffhi, xfflo, 98304);

    // weight prep
    wprep_kernel<64><<<dim3(2048), dim3(256), 0, stream>>>(
        enc_Wih, enc_Whh, enc_bih, enc_bhh, Wcat, bcomb);
    wprep_kernel<32><<<dim3(2048), dim3(256), 0, stream>>>(
        decf_Wih, decf_Whh, decf_bih, decf_bhh, Wcat + WSTRIDE, bcomb + 2048);
    wprep_kernel<32><<<dim3(2048), dim3(256), 0, stream>>>(
        decff_Wih, decff_Whh, decff_bih, decff_bhh, Wcat + 2 * WSTRIDE, bcomb + 4096);

    short* hinhi = hAhi; short* hinlo = hAlo;
    short* houthi = hBhi; short* houtlo = hBlo;

    for (int t = 0; t < 336; ++t) {
        step_mfma<64, false><<<dim3(256), dim3(256), 0, stream>>>(
            xdhi, xdlo, 336, t, Wcat, bcomb,
            hinhi, hinlo, houthi, houtlo, cc, nullptr, nullptr, 0);
        short* s1 = hinhi; hinhi = houthi; houthi = s1;
        short* s2 = hinlo; hinlo = houtlo; houtlo = s2;
    }
    for (int t = 0; t < 96; ++t) {
        step_mfma<32, true><<<dim3(256), dim3(256), 0, stream>>>(
            xfhi, xflo, 96, t, Wcat + WSTRIDE, bcomb + 2048,
            hinhi, hinlo, houthi, houtlo, cc, head_W, parts, t);
        short* s1 = hinhi; hinhi = houthi; houthi = s1;
        short* s2 = hinlo; hinlo = houtlo; houtlo = s2;
    }
    for (int t = 0; t < 48; ++t) {
        step_mfma<32, true><<<dim3(256), dim3(256), 0, stream>>>(
            xffhi, xfflo, 48, t, Wcat + 2 * WSTRIDE, bcomb + 4096,
            hinhi, hinlo, houthi, houtlo, cc, head_W, parts, 96 + t);
        short* s1 = hinhi; hinhi = houthi; houthi = s1;
        short* s2 = hinlo; hinlo = houtlo; houtlo = s2;
    }
    head_finish_kernel<<<dim3((BATCH * NSEQ + 255) / 256), dim3(256), 0, stream>>>(
        parts, head_b, out);
}

// Round 6
// 17253.021 us; speedup vs baseline: 1.9166x; 1.1124x over previous
//
#include <hip/hip_runtime.h>
#include <hip/hip_bf16.h>

#define HDIM 512
#define BATCH 256
#define NSEQ 144
#define KREG 576          // padded per-region K (x|h|pad)
#define KTRIP 1728        // 3 regions: Whi*zhi + Whi*zlo + Wlo*zhi
#define SMEM_BYTES 0

typedef __attribute__((ext_vector_type(8))) short short8;
typedef __attribute__((ext_vector_type(4))) float f32x4;

__device__ __forceinline__ float fast_sigmoid(float x) { return 1.0f / (1.0f + __expf(-x)); }
__device__ __forceinline__ float fast_tanh(float x) {
    x = fminf(fmaxf(x, -12.0f), 12.0f);
    float e = __expf(2.0f * x);
    return (e - 1.0f) / (e + 1.0f);
}
__device__ __forceinline__ short f2bf(float v) {
    __hip_bfloat16 b = __float2bfloat16(v);
    return *reinterpret_cast<short*>(&b);
}
__device__ __forceinline__ float bf2f(short s) {
    __hip_bfloat16 b = *reinterpret_cast<__hip_bfloat16*>(&s);
    return __bfloat162float(b);
}

// Split fp32 -> (hi, lo) bf16 planes. n4 = n/4.
__global__ __launch_bounds__(256)
void xconv_kernel(const float* __restrict__ src, short* __restrict__ hi,
                  short* __restrict__ lo, int n4)
{
    int i = blockIdx.x * 256 + threadIdx.x;
    if (i >= n4) return;
    float4 v = reinterpret_cast<const float4*>(src)[i];
    float vv[4] = {v.x, v.y, v.z, v.w};
    short oh[4], ol[4];
#pragma unroll
    for (int e = 0; e < 4; ++e) {
        short h = f2bf(vv[e]);
        oh[e] = h;
        ol[e] = f2bf(vv[e] - bf2f(h));
    }
    reinterpret_cast<short4*>(hi)[i] = *reinterpret_cast<const short4*>(oh);
    reinterpret_cast<short4*>(lo)[i] = *reinterpret_cast<const short4*>(ol);
}

// Permuted split weights: Wcat[j'][KTRIP], j' = 4*u + gate (i,f,g,o).
// W regions (hi, hi, lo) pair with Z regions (hi, lo, hi). bc[j'] = bih+bhh.
template<int I>
__global__ __launch_bounds__(256)
void wprep_kernel(const float* __restrict__ Wih, const float* __restrict__ Whh,
                  const float* __restrict__ bih, const float* __restrict__ bhh,
                  short* __restrict__ Wcat, float* __restrict__ bc)
{
    const int jp = blockIdx.x;            // 0..2047
    const int u = jp >> 2, g = jp & 3;
    const int srow = g * HDIM + u;
    const int t = threadIdx.x;
    if (t == 255) bc[jp] = bih[srow] + bhh[srow];
    if (t >= KTRIP / 8) return;           // 216 active
    const int kt = t * 8;
    const int region = kt / KREG;
    const int kreg = kt % KREG;
    float v[8];
#pragma unroll
    for (int e = 0; e < 8; ++e) {
        int kr = kreg + e;
        float s;
        if (kr < I)             s = Wih[(size_t)srow * I + kr];
        else if (kr < I + HDIM) s = Whh[(size_t)srow * HDIM + (kr - I)];
        else                    s = 0.0f;
        v[e] = s;
    }
    short o[8];
#pragma unroll
    for (int e = 0; e < 8; ++e) {
        short hi = f2bf(v[e]);
        o[e] = (region == 2) ? f2bf(v[e] - bf2f(hi)) : hi;   // (hi, hi, lo)
    }
    *reinterpret_cast<int4*>(Wcat + (size_t)jp * KTRIP + kt) = *reinterpret_cast<const int4*>(o);
}

struct PArgs {
    const short *xdhi, *xdlo, *xfhi, *xflo, *xffhi, *xfflo;
    const short *Wc0, *Wc1, *Wc2;
    const float *bc0, *bc1, *bc2;
    const float *headW;
    short *h0hi, *h0lo, *h1hi, *h1lo;
    float *parts;
    unsigned *barr;       // 4 groups x 64 unsigned (cnt at +0, gen at +16)
};

// Device-scope sense barrier for nblk blocks sharing {cnt, gen}.
// cnt reset happens BEFORE gen release, so re-arrival at the next barrier
// can't race the reset.
__device__ __forceinline__ void group_barrier(unsigned* cnt, unsigned* gen, unsigned nblk)
{
    __syncthreads();      // all block stores issued (compiler drains vmcnt at barrier)
    if (threadIdx.x == 0) {
        __threadfence();  // release: device-scope writeback
        unsigned g = __hip_atomic_load(gen, __ATOMIC_RELAXED, __HIP_MEMORY_SCOPE_AGENT);
        unsigned arrived = __hip_atomic_fetch_add(cnt, 1u, __ATOMIC_ACQ_REL,
                                                  __HIP_MEMORY_SCOPE_AGENT) + 1u;
        if (arrived == nblk) {
            __hip_atomic_store(cnt, 0u, __ATOMIC_RELAXED, __HIP_MEMORY_SCOPE_AGENT);
            __hip_atomic_store(gen, g + 1u, __ATOMIC_RELEASE, __HIP_MEMORY_SCOPE_AGENT);
        } else {
            while (__hip_atomic_load(gen, __ATOMIC_ACQUIRE, __HIP_MEMORY_SCOPE_AGENT) == g)
                __builtin_amdgcn_s_sleep(8);
        }
        __threadfence();  // acquire: invalidate stale cached lines
    }
    __syncthreads();
}

// One LSTM step. Wave w owns batch rows [bm*64 + w*16, +16) x gate cols
// [bn*32, +32). A-frags stream global->reg (4-deep pipeline); B-frags from
// swizzled LDS W. Epilogue: 4-lane gate gather, c in LDS, h staged to LDS.
template<int KSTEPS, int I>
__device__ __forceinline__ void do_step(
    const short* __restrict__ Wl,
    float* __restrict__ c_l, float* __restrict__ hout_l,
    const float* __restrict__ bcl, const float* __restrict__ hwl,
    const short* __restrict__ xhi, const short* __restrict__ xlo,
    int T, int tloc,
    const short* __restrict__ hhi, const short* __restrict__ hlo,
    short* __restrict__ hohi, short* __restrict__ holo,
    float* __restrict__ parts, int seq_t, bool head,
    int bm, int bn, int tid)
{
    constexpr int NK = 3 * KSTEPS;
    const int w = tid >> 6, lane = tid & 63;
    const int l15 = lane & 15, lg = lane >> 4, gs = l15 & 3;
    const int brow = bm * 64 + w * 16 + l15;
    const int lg8 = lg * 8;

    auto aload = [&](int ks) -> short8 {
        int region = ks / KSTEPS;
        int kreg = (ks % KSTEPS) * 32;
        const short* px = (region == 1) ? xlo : xhi;
        const short* ph = (region == 1) ? hlo : hhi;
        const short* p;
        if (kreg < I) p = px + ((size_t)brow * T + tloc) * I + kreg + lg8;
        else          p = ph + ((size_t)brow << 9) + (kreg - I) + lg8;
        return *reinterpret_cast<const short8*>(p);
    };

    f32x4 acc[2] = {{0.f,0.f,0.f,0.f}, {0.f,0.f,0.f,0.f}};
    short8 ap[4];
    ap[0] = aload(0); ap[1] = aload(1); ap[2] = aload(2); ap[3] = aload(3);

    const int rl0 = l15, rl1 = 16 + l15;
    const short* wb0 = Wl + rl0 * KTRIP;
    const short* wb1 = Wl + rl1 * KTRIP;
    const int x0 = rl0 & 7, x1 = rl1 & 7;

#pragma unroll
    for (int ks = 0; ks < NK; ++ks) {
        int g = (ks / KSTEPS) * 72 + (ks % KSTEPS) * 4 + lg;
        short8 b0 = *reinterpret_cast<const short8*>(wb0 + ((g ^ x0) << 3));
        short8 b1 = *reinterpret_cast<const short8*>(wb1 + ((g ^ x1) << 3));
        acc[0] = __builtin_amdgcn_mfma_f32_16x16x32_bf16(ap[ks & 3], b0, acc[0], 0, 0, 0);
        acc[1] = __builtin_amdgcn_mfma_f32_16x16x32_bf16(ap[ks & 3], b1, acc[1], 0, 0, 0);
        if (ks + 4 < NK) ap[ks & 3] = aload(ks + 4);
    }

    // Epilogue: D row = lg*4+r (batch), col = l15 -> j'. 4-lane groups = i,f,g,o.
    float hp[4] = {0.f, 0.f, 0.f, 0.f};
#pragma unroll
    for (int nf = 0; nf < 2; ++nf) {
        float bias = bcl[nf * 16 + l15];
        int ul = nf * 4 + (l15 >> 2);
#pragma unroll
        for (int r = 0; r < 4; ++r) {
            float v = acc[nf][r] + bias;
            float act = (gs == 2) ? fast_tanh(v) : fast_sigmoid(v);
            int base = lane & ~3;
            float ai = __shfl(act, base,     64);
            float af = __shfl(act, base | 1, 64);
            float ag = __shfl(act, base | 2, 64);
            float ao = __shfl(act, base | 3, 64);
            int bl = w * 16 + lg * 4 + r;
            int ci = bl * 8 + ul;
            float cn = af * c_l[ci] + ai * ag;
            float hn = ao * fast_tanh(cn);
            if (gs == 0) { c_l[ci] = cn; hout_l[ci] = hn; }
            if (head) {
                float p = (gs == 0) ? hn * hwl[ul] : 0.f;
                p += __shfl_xor(p, 4, 64);
                p += __shfl_xor(p, 8, 64);
                hp[r] += p;
            }
        }
    }
    if (head && l15 == 0) {
#pragma unroll
        for (int r = 0; r < 4; ++r) {
            int bg = bm * 64 + w * 16 + lg * 4 + r;
            parts[((size_t)bg * NSEQ + seq_t) * 64 + bn] = hp[r];
        }
    }
    __syncthreads();
    // h copy: 64 threads, 16B hi + 16B lo per batch row
    if (tid < 64) {
        short oh[8], ol[8];
#pragma unroll
        for (int e = 0; e < 8; ++e) {
            float hn = hout_l[tid * 8 + e];
            short h = f2bf(hn);
            oh[e] = h;
            ol[e] = f2bf(hn - bf2f(h));
        }
        size_t off = ((size_t)(bm * 64 + tid) << 9) + bn * 8;
        *reinterpret_cast<int4*>(hohi + off) = *reinterpret_cast<const int4*>(oh);
        *reinterpret_cast<int4*>(holo + off) = *reinterpret_cast<const int4*>(ol);
    }
}

__global__ __launch_bounds__(256)
void lstm_persist(PArgs a)
{
    __shared__ short Wl[32 * KTRIP];      // 110592 B (static: gfx950 LDS = 160KB)
    __shared__ float c_l[512];
    __shared__ float hout_l[512];
    __shared__ float bcl[32];
    __shared__ float hwl[8];

    const int tid = threadIdx.x;
    const int bn = blockIdx.x & 63;
    const int bm = blockIdx.x >> 6;
    unsigned* cnt = a.barr + bm * 64;
    unsigned* gen = a.barr + bm * 64 + 16;

    for (int i = tid; i < 512; i += 256) c_l[i] = 0.f;
    if (tid < 8) hwl[tid] = a.headW[bn * 8 + tid];

    for (int s = 0; s < 480; ++s) {
        const short *xhi, *xlo, *Wc;
        const float* bc;
        int T, tloc, I_;
        if (s < 336) {
            xhi = a.xdhi; xlo = a.xdlo; Wc = a.Wc0; bc = a.bc0;
            T = 336; tloc = s; I_ = 64;
        } else if (s < 432) {
            xhi = a.xfhi; xlo = a.xflo; Wc = a.Wc1; bc = a.bc1;
            T = 96; tloc = s - 336; I_ = 32;
        } else {
            xhi = a.xffhi; xlo = a.xfflo; Wc = a.Wc2; bc = a.bc2;
            T = 48; tloc = s - 432; I_ = 32;
        }
        if (s == 0 || s == 336 || s == 432) {
            __syncthreads();
            int row = tid >> 3, g0 = tid & 7;
            const short* src = Wc + (size_t)(bn * 32 + row) * KTRIP;
#pragma unroll
            for (int i2 = 0; i2 < 27; ++i2) {
                int g = g0 + i2 * 8;
                *reinterpret_cast<int4*>(Wl + row * KTRIP + ((g ^ (row & 7)) << 3)) =
                    *reinterpret_cast<const int4*>(src + g * 8);
            }
            if (tid < 32) bcl[tid] = bc[bn * 32 + tid];
            __syncthreads();
        }
        const int par = s & 1;
        const short* hhi = par ? a.h1hi : a.h0hi;
        const short* hlo = par ? a.h1lo : a.h0lo;
        short* hohi = par ? a.h0hi : a.h1hi;
        short* holo = par ? a.h0lo : a.h1lo;
        bool head = s >= 336;
        int seq_t = s - 336;
        if (I_ == 64)
            do_step<18, 64>(Wl, c_l, hout_l, bcl, hwl, xhi, xlo, T, tloc,
                            hhi, hlo, hohi, holo, a.parts, seq_t, head, bm, bn, tid);
        else
            do_step<17, 32>(Wl, c_l, hout_l, bcl, hwl, xhi, xlo, T, tloc,
                            hhi, hlo, hohi, holo, a.parts, seq_t, head, bm, bn, tid);
        group_barrier(cnt, gen, 64u);
    }
}

__global__ __launch_bounds__(256)
void head_finish_kernel(const float* __restrict__ partials,
                        const float* __restrict__ head_b,
                        float* __restrict__ out)
{
    int idx = blockIdx.x * 256 + threadIdx.x;   // b*144 + t
    if (idx >= BATCH * NSEQ) return;
    const float* p = partials + (size_t)idx * 64;
    float s = head_b[0];
#pragma unroll
    for (int i = 0; i < 64; ++i) s += p[i];
    out[idx] = s;
}

extern "C" void kernel_launch(void* const* d_in, const int* in_sizes, int n_in,
                              void* d_out, int out_size, void* d_ws, size_t ws_size,
                              hipStream_t stream) {
    const float* x_d      = (const float*)d_in[0];
    const float* x_f      = (const float*)d_in[1];
    const float* x_ff     = (const float*)d_in[2];
    const float* enc_Wih  = (const float*)d_in[3];
    const float* enc_Whh  = (const float*)d_in[4];
    const float* enc_bih  = (const float*)d_in[5];
    const float* enc_bhh  = (const float*)d_in[6];
    const float* decf_Wih = (const float*)d_in[7];
    const float* decf_Whh = (const float*)d_in[8];
    const float* decf_bih = (const float*)d_in[9];
    const float* decf_bhh = (const float*)d_in[10];
    const float* decff_Wih = (const float*)d_in[11];
    const float* decff_Whh = (const float*)d_in[12];
    const float* decff_bih = (const float*)d_in[13];
    const float* decff_bhh = (const float*)d_in[14];
    const float* head_W   = (const float*)d_in[15];
    const float* head_b   = (const float*)d_in[16];
    float* out = (float*)d_out;

    char* base = (char*)d_ws;
    short* h0hi  = (short*)(base + 0);           // 262144 B
    short* h0lo  = (short*)(base + 262144);      // 262144
    short* h1hi  = (short*)(base + 524288);      // 262144
    short* h1lo  = (short*)(base + 786432);      // 262144
    unsigned* barr = (unsigned*)(base + 1048576);// 1024
    float* parts = (float*)(base + 1049600);     // 9437184
    float* bcomb = (float*)(base + 10486784);    // 24576
    short* Wcat  = (short*)(base + 10511360);    // 21233664
    short* xdhi  = (short*)(base + 31745024);    // 11010048
    short* xdlo  = (short*)(base + 42755072);    // 11010048
    short* xfhi  = (short*)(base + 53765120);    // 1572864
    short* xflo  = (short*)(base + 55337984);    // 1572864
    short* xffhi = (short*)(base + 56910848);    // 786432
    short* xfflo = (short*)(base + 57697280);    // 786432
    const size_t WSTRIDE = (size_t)2048 * KTRIP;

    // zero h0, h1, barrier state
    hipMemsetAsync(base, 0, 1049600 + 1024, stream);

    // input split-precision conversion
    xconv_kernel<<<dim3(5376), dim3(256), 0, stream>>>(x_d,  xdhi,  xdlo,  1376256);
    xconv_kernel<<<dim3(768),  dim3(256), 0, stream>>>(x_f,  xfhi,  xflo,  196608);
    xconv_kernel<<<dim3(384),  dim3(256), 0, stream>>>(x_ff, xffhi, xfflo, 98304);

    // weight prep
    wprep_kernel<64><<<dim3(2048), dim3(256), 0, stream>>>(
        enc_Wih, enc_Whh, enc_bih, enc_bhh, Wcat, bcomb);
    wprep_kernel<32><<<dim3(2048), dim3(256), 0, stream>>>(
        decf_Wih, decf_Whh, decf_bih, decf_bhh, Wcat + WSTRIDE, bcomb + 2048);
    wprep_kernel<32><<<dim3(2048), dim3(256), 0, stream>>>(
        decff_Wih, decff_Whh, decff_bih, decff_bhh, Wcat + 2 * WSTRIDE, bcomb + 4096);

    // persistent recurrence (one dispatch for all 480 steps)
    PArgs pa;
    pa.xdhi = xdhi; pa.xdlo = xdlo; pa.xfhi = xfhi; pa.xflo = xflo;
    pa.xffhi = xffhi; pa.xfflo = xfflo;
    pa.Wc0 = Wcat; pa.Wc1 = Wcat + WSTRIDE; pa.Wc2 = Wcat + 2 * WSTRIDE;
    pa.bc0 = bcomb; pa.bc1 = bcomb + 2048; pa.bc2 = bcomb + 4096;
    pa.headW = head_W;
    pa.h0hi = h0hi; pa.h0lo = h0lo; pa.h1hi = h1hi; pa.h1lo = h1lo;
    pa.parts = parts;
    pa.barr = barr;
    void* kargs[] = { &pa };
    hipError_t ce = hipLaunchCooperativeKernel((const void*)lstm_persist,
                                               dim3(256), dim3(256), kargs,
                                               SMEM_BYTES, stream);
    if (ce != hipSuccess) {
        // fallback: plain launch (grid=256 at 1 block/CU is co-resident on 256 CUs;
        // barrier is hand-rolled, no cg dependency)
        lstm_persist<<<dim3(256), dim3(256), 0, stream>>>(pa);
    }

    head_finish_kernel<<<dim3((BATCH * NSEQ + 255) / 256), dim3(256), 0, stream>>>(
        parts, head_b, out);
}

// Round 7
// 6859.048 us; speedup vs baseline: 4.8210x; 2.5154x over previous
//
#include <hip/hip_runtime.h>
#include <hip/hip_bf16.h>

#define HDIM 512
#define BATCH 256
#define NSEQ 144
#define KREG 576          // padded per-region K (x|h|pad)
#define KTRIP 1728        // 3 regions: Whi*zhi + Whi*zlo + Wlo*zhi

typedef __attribute__((ext_vector_type(8))) short short8;
typedef __attribute__((ext_vector_type(4))) float f32x4;
typedef __attribute__((ext_vector_type(4))) int int4v;

__device__ __forceinline__ float fast_sigmoid(float x) { return 1.0f / (1.0f + __expf(-x)); }
__device__ __forceinline__ float fast_tanh(float x) {
    x = fminf(fmaxf(x, -12.0f), 12.0f);
    float e = __expf(2.0f * x);
    return (e - 1.0f) / (e + 1.0f);
}
__device__ __forceinline__ short f2bf(float v) {
    __hip_bfloat16 b = __float2bfloat16(v);
    return *reinterpret_cast<short*>(&b);
}
__device__ __forceinline__ float bf2f(short s) {
    __hip_bfloat16 b = *reinterpret_cast<__hip_bfloat16*>(&s);
    return __bfloat162float(b);
}

// Device-coherent 16B load/store: sc0 sc1 bypass the (non-coherent, per-XCD) L2
// and hit the L3 coherence point. This is how h crosses XCDs WITHOUT any
// buffer_wbl2/buffer_inv (the per-step killers in R6).
__device__ __forceinline__ short8 coh_load8(const short* p) {
    short8 r;
    asm volatile("global_load_dwordx4 %0, %1, off sc0 sc1" : "=v"(r) : "v"(p));
    return r;   // NOT ready until s_waitcnt vmcnt(0) — batched by caller
}
__device__ __forceinline__ void coh_store16(short* p, int4v v) {
    asm volatile("global_store_dwordx4 %0, %1, off sc0 sc1" :: "v"(p), "v"(v) : "memory");
}

// Split fp32 -> (hi, lo) bf16 planes. n4 = n/4.
__global__ __launch_bounds__(256)
void xconv_kernel(const float* __restrict__ src, short* __restrict__ hi,
                  short* __restrict__ lo, int n4)
{
    int i = blockIdx.x * 256 + threadIdx.x;
    if (i >= n4) return;
    float4 v = reinterpret_cast<const float4*>(src)[i];
    float vv[4] = {v.x, v.y, v.z, v.w};
    short oh[4], ol[4];
#pragma unroll
    for (int e = 0; e < 4; ++e) {
        short h = f2bf(vv[e]);
        oh[e] = h;
        ol[e] = f2bf(vv[e] - bf2f(h));
    }
    reinterpret_cast<short4*>(hi)[i] = *reinterpret_cast<const short4*>(oh);
    reinterpret_cast<short4*>(lo)[i] = *reinterpret_cast<const short4*>(ol);
}

// Permuted split weights: Wcat[j'][KTRIP], j' = 4*u + gate (i,f,g,o).
// W regions (hi, hi, lo) pair with Z regions (hi, lo, hi). bc[j'] = bih+bhh.
template<int I>
__global__ __launch_bounds__(256)
void wprep_kernel(const float* __restrict__ Wih, const float* __restrict__ Whh,
                  const float* __restrict__ bih, const float* __restrict__ bhh,
                  short* __restrict__ Wcat, float* __restrict__ bc)
{
    const int jp = blockIdx.x;            // 0..2047
    const int u = jp >> 2, g = jp & 3;
    const int srow = g * HDIM + u;
    const int t = threadIdx.x;
    if (t == 255) bc[jp] = bih[srow] + bhh[srow];
    if (t >= KTRIP / 8) return;           // 216 active
    const int kt = t * 8;
    const int region = kt / KREG;
    const int kreg = kt % KREG;
    float v[8];
#pragma unroll
    for (int e = 0; e < 8; ++e) {
        int kr = kreg + e;
        float s;
        if (kr < I)             s = Wih[(size_t)srow * I + kr];
        else if (kr < I + HDIM) s = Whh[(size_t)srow * HDIM + (kr - I)];
        else                    s = 0.0f;
        v[e] = s;
    }
    short o[8];
#pragma unroll
    for (int e = 0; e < 8; ++e) {
        short hi = f2bf(v[e]);
        o[e] = (region == 2) ? f2bf(v[e] - bf2f(hi)) : hi;   // (hi, hi, lo)
    }
    *reinterpret_cast<int4*>(Wcat + (size_t)jp * KTRIP + kt) = *reinterpret_cast<const int4*>(o);
}

struct PArgs {
    const short *xdhi, *xdlo, *xfhi, *xflo, *xffhi, *xfflo;
    const short *Wc0, *Wc1, *Wc2;
    const float *bc0, *bc1, *bc2;
    const float *headW;
    short *h0hi, *h0lo, *h1hi, *h1lo;
    float *parts;
    unsigned *barr;       // 4 groups x 64 unsigned (cnt at +0, gen at +16)
};

// Relaxed sense barrier, AGENT-scope atomics (coherent at L3), NO threadfence
// (no buffer_wbl2/buffer_inv). Data ordering: h goes through sc0/sc1 path;
// __syncthreads drains vmcnt before arrival.
__device__ __forceinline__ void group_barrier(unsigned* cnt, unsigned* gen, unsigned nblk)
{
    __syncthreads();      // drains vmcnt(0): wave-0's coh h-stores are at L3
    if (threadIdx.x == 0) {
        unsigned g = __hip_atomic_load(gen, __ATOMIC_RELAXED, __HIP_MEMORY_SCOPE_AGENT);
        unsigned arrived = __hip_atomic_fetch_add(cnt, 1u, __ATOMIC_RELAXED,
                                                  __HIP_MEMORY_SCOPE_AGENT) + 1u;
        if (arrived == nblk) {
            __hip_atomic_store(cnt, 0u, __ATOMIC_RELAXED, __HIP_MEMORY_SCOPE_AGENT);
            __hip_atomic_store(gen, g + 1u, __ATOMIC_RELAXED, __HIP_MEMORY_SCOPE_AGENT);
        } else {
            while (__hip_atomic_load(gen, __ATOMIC_RELAXED, __HIP_MEMORY_SCOPE_AGENT) == g)
                __builtin_amdgcn_s_sleep(1);
        }
    }
    __syncthreads();
}

// One LSTM step. Wave w owns batch rows [bm*64 + w*16, +16) x gate cols
// [bn*32, +32). ALL unique A-frags (hi+lo planes; region 2 reuses region 0's
// hi frags) are issued up-front -> one vmcnt(0) -> 108 unrolled MFMAs.
template<int KSTEPS, int I>
__device__ __forceinline__ void do_step(
    const short* __restrict__ Wl,
    float* __restrict__ c_l, float* __restrict__ hout_l,
    const float* __restrict__ bcl, const float* __restrict__ hwl,
    const short* __restrict__ xhi, const short* __restrict__ xlo,
    int T, int tloc,
    const short* __restrict__ hhi, const short* __restrict__ hlo,
    short* __restrict__ hohi, short* __restrict__ holo,
    float* __restrict__ parts, int seq_t, bool head,
    int bm, int bn, int tid)
{
    constexpr int XF = I / 32;            // x frags per region
    const int w = tid >> 6, lane = tid & 63;
    const int l15 = lane & 15, lg = lane >> 4, gs = l15 & 3;
    const int brow = bm * 64 + w * 16 + l15;
    const int lg8 = lg * 8;

    // ---- A-fragment load phase: all 2*KSTEPS unique frags up-front ----
    short8 aphi[KSTEPS], aplo[KSTEPS];
    {
        const short* xh = xhi + ((size_t)brow * T + tloc) * I + lg8;
        const short* xl = xlo + ((size_t)brow * T + tloc) * I + lg8;
        const short* hh = hhi + ((size_t)brow << 9) + lg8;
        const short* hl = hlo + ((size_t)brow << 9) + lg8;
#pragma unroll
        for (int ks = 0; ks < XF; ++ks) {         // x: plain cached loads (L2-hot)
            aphi[ks] = *reinterpret_cast<const short8*>(xh + ks * 32);
            aplo[ks] = *reinterpret_cast<const short8*>(xl + ks * 32);
        }
#pragma unroll
        for (int ks = XF; ks < KSTEPS; ++ks) {    // h: coherent L3 loads
            aphi[ks] = coh_load8(hh + (ks - XF) * 32);
            aplo[ks] = coh_load8(hl + (ks - XF) * 32);
        }
    }
    asm volatile("s_waitcnt vmcnt(0)" ::: "memory");
    __builtin_amdgcn_sched_barrier(0);    // rule #18: no MFMA hoists above the wait

    // ---- MFMA phase: fully unrolled, static indexing ----
    f32x4 acc[2] = {{0.f,0.f,0.f,0.f}, {0.f,0.f,0.f,0.f}};
    const short* wb0 = Wl + l15 * KTRIP;
    const short* wb1 = Wl + (16 + l15) * KTRIP;
    const int x0 = l15 & 7, x1 = (16 + l15) & 7;
#pragma unroll
    for (int ks = 0; ks < 3 * KSTEPS; ++ks) {
        const int r = ks / KSTEPS, ksub = ks % KSTEPS;
        short8 a = (r == 1) ? aplo[ksub] : aphi[ksub];   // region 2 reuses hi
        int g = r * 72 + ksub * 4 + lg;
        short8 b0 = *reinterpret_cast<const short8*>(wb0 + ((g ^ x0) << 3));
        short8 b1 = *reinterpret_cast<const short8*>(wb1 + ((g ^ x1) << 3));
        acc[0] = __builtin_amdgcn_mfma_f32_16x16x32_bf16(a, b0, acc[0], 0, 0, 0);
        acc[1] = __builtin_amdgcn_mfma_f32_16x16x32_bf16(a, b1, acc[1], 0, 0, 0);
    }

    // ---- Epilogue: D row = lg*4+r (batch), col = l15 -> j'; 4-lane gate groups ----
    float hp[4] = {0.f, 0.f, 0.f, 0.f};
#pragma unroll
    for (int nf = 0; nf < 2; ++nf) {
        float bias = bcl[nf * 16 + l15];
        int ul = nf * 4 + (l15 >> 2);
#pragma unroll
        for (int r = 0; r < 4; ++r) {
            float v = acc[nf][r] + bias;
            float act = (gs == 2) ? fast_tanh(v) : fast_sigmoid(v);
            int base = lane & ~3;
            float ai = __shfl(act, base,     64);
            float af = __shfl(act, base | 1, 64);
            float ag = __shfl(act, base | 2, 64);
            float ao = __shfl(act, base | 3, 64);
            int bl = w * 16 + lg * 4 + r;
            int ci = bl * 8 + ul;
            float cn = af * c_l[ci] + ai * ag;
            float hn = ao * fast_tanh(cn);
            if (gs == 0) { c_l[ci] = cn; hout_l[ci] = hn; }
            if (head) {
                float p = (gs == 0) ? hn * hwl[ul] : 0.f;
                p += __shfl_xor(p, 4, 64);
                p += __shfl_xor(p, 8, 64);
                hp[r] += p;
            }
        }
    }
    if (head && l15 == 0) {
#pragma unroll
        for (int r = 0; r < 4; ++r) {
            int bg = bm * 64 + w * 16 + lg * 4 + r;
            parts[((size_t)bg * NSEQ + seq_t) * 64 + bn] = hp[r];   // plain (read next dispatch)
        }
    }
    __syncthreads();
    // h copy by wave 0: coherent stores to the L3 exchange buffers
    if (tid < 64) {
        short oh[8], ol[8];
#pragma unroll
        for (int e = 0; e < 8; ++e) {
            float hn = hout_l[tid * 8 + e];
            short h = f2bf(hn);
            oh[e] = h;
            ol[e] = f2bf(hn - bf2f(h));
        }
        size_t off = ((size_t)(bm * 64 + tid) << 9) + bn * 8;
        coh_store16(hohi + off, *reinterpret_cast<const int4v*>(oh));
        coh_store16(holo + off, *reinterpret_cast<const int4v*>(ol));
    }
}

__global__ __launch_bounds__(256, 1)
void lstm_persist(PArgs a)
{
    __shared__ short Wl[32 * KTRIP];      // 110592 B static
    __shared__ float c_l[512];
    __shared__ float hout_l[512];
    __shared__ float bcl[32];
    __shared__ float hwl[8];

    const int tid = threadIdx.x;
    const int bn = blockIdx.x & 63;
    const int bm = blockIdx.x >> 6;
    unsigned* cnt = a.barr + bm * 64;
    unsigned* gen = a.barr + bm * 64 + 16;

    for (int i = tid; i < 512; i += 256) c_l[i] = 0.f;
    if (tid < 8) hwl[tid] = a.headW[bn * 8 + tid];

    for (int s = 0; s < 480; ++s) {
        const short *xhi, *xlo, *Wc;
        const float* bc;
        int T, tloc, I_;
        if (s < 336) {
            xhi = a.xdhi; xlo = a.xdlo; Wc = a.Wc0; bc = a.bc0;
            T = 336; tloc = s; I_ = 64;
        } else if (s < 432) {
            xhi = a.xfhi; xlo = a.xflo; Wc = a.Wc1; bc = a.bc1;
            T = 96; tloc = s - 336; I_ = 32;
        } else {
            xhi = a.xffhi; xlo = a.xfflo; Wc = a.Wc2; bc = a.bc2;
            T = 48; tloc = s - 432; I_ = 32;
        }
        if (s == 0 || s == 336 || s == 432) {
            __syncthreads();
            int row = tid >> 3, g0 = tid & 7;
            const short* src = Wc + (size_t)(bn * 32 + row) * KTRIP;
#pragma unroll
            for (int i2 = 0; i2 < 27; ++i2) {
                int g = g0 + i2 * 8;
                *reinterpret_cast<int4*>(Wl + row * KTRIP + ((g ^ (row & 7)) << 3)) =
                    *reinterpret_cast<const int4*>(src + g * 8);
            }
            if (tid < 32) bcl[tid] = bc[bn * 32 + tid];
            __syncthreads();
        }
        const int par = s & 1;
        const short* hhi = par ? a.h1hi : a.h0hi;
        const short* hlo = par ? a.h1lo : a.h0lo;
        short* hohi = par ? a.h0hi : a.h1hi;
        short* holo = par ? a.h0lo : a.h1lo;
        bool head = s >= 336;
        int seq_t = s - 336;
        if (I_ == 64)
            do_step<18, 64>(Wl, c_l, hout_l, bcl, hwl, xhi, xlo, T, tloc,
                            hhi, hlo, hohi, holo, a.parts, seq_t, head, bm, bn, tid);
        else
            do_step<17, 32>(Wl, c_l, hout_l, bcl, hwl, xhi, xlo, T, tloc,
                            hhi, hlo, hohi, holo, a.parts, seq_t, head, bm, bn, tid);
        group_barrier(cnt, gen, 64u);
    }
}

__global__ __launch_bounds__(256)
void head_finish_kernel(const float* __restrict__ partials,
                        const float* __restrict__ head_b,
                        float* __restrict__ out)
{
    int idx = blockIdx.x * 256 + threadIdx.x;   // b*144 + t
    if (idx >= BATCH * NSEQ) return;
    const float* p = partials + (size_t)idx * 64;
    float s = head_b[0];
#pragma unroll
    for (int i = 0; i < 64; ++i) s += p[i];
    out[idx] = s;
}

extern "C" void kernel_launch(void* const* d_in, const int* in_sizes, int n_in,
                              void* d_out, int out_size, void* d_ws, size_t ws_size,
                              hipStream_t stream) {
    const float* x_d      = (const float*)d_in[0];
    const float* x_f      = (const float*)d_in[1];
    const float* x_ff     = (const float*)d_in[2];
    const float* enc_Wih  = (const float*)d_in[3];
    const float* enc_Whh  = (const float*)d_in[4];
    const float* enc_bih  = (const float*)d_in[5];
    const float* enc_bhh  = (const float*)d_in[6];
    const float* decf_Wih = (const float*)d_in[7];
    const float* decf_Whh = (const float*)d_in[8];
    const float* decf_bih = (const float*)d_in[9];
    const float* decf_bhh = (const float*)d_in[10];
    const float* decff_Wih = (const float*)d_in[11];
    const float* decff_Whh = (const float*)d_in[12];
    const float* decff_bih = (const float*)d_in[13];
    const float* decff_bhh = (const float*)d_in[14];
    const float* head_W   = (const float*)d_in[15];
    const float* head_b   = (const float*)d_in[16];
    float* out = (float*)d_out;

    char* base = (char*)d_ws;
    short* h0hi  = (short*)(base + 0);           // 262144 B
    short* h0lo  = (short*)(base + 262144);      // 262144
    short* h1hi  = (short*)(base + 524288);      // 262144
    short* h1lo  = (short*)(base + 786432);      // 262144
    unsigned* barr = (unsigned*)(base + 1048576);// 1024
    float* parts = (float*)(base + 1049600);     // 9437184
    float* bcomb = (float*)(base + 10486784);    // 24576
    short* Wcat  = (short*)(base + 10511360);    // 21233664
    short* xdhi  = (short*)(base + 31745024);    // 11010048
    short* xdlo  = (short*)(base + 42755072);    // 11010048
    short* xfhi  = (short*)(base + 53765120);    // 1572864
    short* xflo  = (short*)(base + 55337984);    // 1572864
    short* xffhi = (short*)(base + 56910848);    // 786432
    short* xfflo = (short*)(base + 57697280);    // 786432
    const size_t WSTRIDE = (size_t)2048 * KTRIP;

    // zero h0, h1, barrier state
    hipMemsetAsync(base, 0, 1049600 + 1024, stream);

    // input split-precision conversion
    xconv_kernel<<<dim3(5376), dim3(256), 0, stream>>>(x_d,  xdhi,  xdlo,  1376256);
    xconv_kernel<<<dim3(768),  dim3(256), 0, stream>>>(x_f,  xfhi,  xflo,  196608);
    xconv_kernel<<<dim3(384),  dim3(256), 0, stream>>>(x_ff, xffhi, xfflo, 98304);

    // weight prep
    wprep_kernel<64><<<dim3(2048), dim3(256), 0, stream>>>(
        enc_Wih, enc_Whh, enc_bih, enc_bhh, Wcat, bcomb);
    wprep_kernel<32><<<dim3(2048), dim3(256), 0, stream>>>(
        decf_Wih, decf_Whh, decf_bih, decf_bhh, Wcat + WSTRIDE, bcomb + 2048);
    wprep_kernel<32><<<dim3(2048), dim3(256), 0, stream>>>(
        decff_Wih, decff_Whh, decff_bih, decff_bhh, Wcat + 2 * WSTRIDE, bcomb + 4096);

    // persistent recurrence (one dispatch for all 480 steps)
    PArgs pa;
    pa.xdhi = xdhi; pa.xdlo = xdlo; pa.xfhi = xfhi; pa.xflo = xflo;
    pa.xffhi = xffhi; pa.xfflo = xfflo;
    pa.Wc0 = Wcat; pa.Wc1 = Wcat + WSTRIDE; pa.Wc2 = Wcat + 2 * WSTRIDE;
    pa.bc0 = bcomb; pa.bc1 = bcomb + 2048; pa.bc2 = bcomb + 4096;
    pa.headW = head_W;
    pa.h0hi = h0hi; pa.h0lo = h0lo; pa.h1hi = h1hi; pa.h1lo = h1lo;
    pa.parts = parts;
    pa.barr = barr;
    void* kargs[] = { &pa };
    hipError_t ce = hipLaunchCooperativeKernel((const void*)lstm_persist,
                                               dim3(256), dim3(256), kargs,
                                               0, stream);
    if (ce != hipSuccess) {
        lstm_persist<<<dim3(256), dim3(256), 0, stream>>>(pa);
    }

    head_finish_kernel<<<dim3((BATCH * NSEQ + 255) / 256), dim3(256), 0, stream>>>(
        parts, head_b, out);
}

// Round 8
// 4022.728 us; speedup vs baseline: 8.2201x; 1.7051x over previous
//
#include <hip/hip_runtime.h>
#include <hip/hip_bf16.h>

#define HDIM 512
#define BATCH 256
#define NSEQ 144

typedef __attribute__((ext_vector_type(8))) short short8;
typedef __attribute__((ext_vector_type(4))) float f32x4;
typedef __attribute__((ext_vector_type(4))) int int4v;

__device__ __forceinline__ float fast_sigmoid(float x) { return 1.0f / (1.0f + __expf(-x)); }
__device__ __forceinline__ float fast_tanh(float x) {
    x = fminf(fmaxf(x, -12.0f), 12.0f);
    float e = __expf(2.0f * x);
    return (e - 1.0f) / (e + 1.0f);
}
__device__ __forceinline__ short f2bf(float v) {
    __hip_bfloat16 b = __float2bfloat16(v);
    return *reinterpret_cast<short*>(&b);
}
__device__ __forceinline__ float bf2f(short s) {
    __hip_bfloat16 b = *reinterpret_cast<__hip_bfloat16*>(&s);
    return __bfloat162float(b);
}

// Agent-scope (cross-XCD, LLC coherence point) ops: sc1 only — NOT sc0 sc1
// (system scope, may push past the LLC). No wbl2/inv anywhere.
__device__ __forceinline__ void agent_load8(short8& d, const short* p) {
    asm volatile("global_load_dwordx4 %0, %1, off sc1" : "=v"(d) : "v"(p));
}
__device__ __forceinline__ void plain_load8(short8& d, const short* p) {
    asm volatile("global_load_dwordx4 %0, %1, off" : "=v"(d) : "v"(p));
}
__device__ __forceinline__ void agent_store16(short* p, int4v v) {
    asm volatile("global_store_dwordx4 %0, %1, off sc1" :: "v"(p), "v"(v) : "memory");
}

// Split fp32 -> (hi, lo) bf16 planes. n4 = n/4.
__global__ __launch_bounds__(256)
void xconv_kernel(const float* __restrict__ src, short* __restrict__ hi,
                  short* __restrict__ lo, int n4)
{
    int i = blockIdx.x * 256 + threadIdx.x;
    if (i >= n4) return;
    float4 v = reinterpret_cast<const float4*>(src)[i];
    float vv[4] = {v.x, v.y, v.z, v.w};
    short oh[4], ol[4];
#pragma unroll
    for (int e = 0; e < 4; ++e) {
        short h = f2bf(vv[e]);
        oh[e] = h;
        ol[e] = f2bf(vv[e] - bf2f(h));
    }
    reinterpret_cast<short4*>(hi)[i] = *reinterpret_cast<const short4*>(oh);
    reinterpret_cast<short4*>(lo)[i] = *reinterpret_cast<const short4*>(ol);
}

// Permuted split weights, j' = 4*u + gate (i,f,g,o), K layout per row:
//   region0: hi([Wih|Whh])        (R0S = (I+512)/32 ksteps, exact)
//   region1: hi(Wih) x-cols only  (2 ksteps, zero-padded past I)
//   region2: lo([Wih|Whh])        (R0S ksteps)
// Pairs with Z = ([xhi|hhi], [xlo|pad], [xhi|hhi]). h-lo term dropped.
template<int I>
__global__ __launch_bounds__(256)
void wprep_kernel(const float* __restrict__ Wih, const float* __restrict__ Whh,
                  const float* __restrict__ bih, const float* __restrict__ bhh,
                  short* __restrict__ Wcat, float* __restrict__ bc)
{
    constexpr int R0S = (I + 512) / 32;
    constexpr int NKS = 2 * R0S + 2;
    constexpr int KTOT = NKS * 32;
    constexpr int GR = NKS * 4;           // granules per row (152 / 144)
    const int jp = blockIdx.x;            // 0..2047
    const int u = jp >> 2, g = jp & 3;
    const int srow = g * HDIM + u;
    const int t = threadIdx.x;
    if (t == 255) bc[jp] = bih[srow] + bhh[srow];
    if (t >= GR) return;
    int region, kr;
    if (t < R0S * 4)          { region = 0; kr = t * 8; }
    else if (t < R0S * 4 + 8) { region = 1; kr = (t - R0S * 4) * 8; }
    else                      { region = 2; kr = (t - R0S * 4 - 8) * 8; }
    short o[8];
#pragma unroll
    for (int e = 0; e < 8; ++e) {
        int k = kr + e;
        if (region == 1) {
            o[e] = (k < I) ? f2bf(Wih[(size_t)srow * I + k]) : (short)0;
        } else {
            float s = (k < I) ? Wih[(size_t)srow * I + k]
                              : Whh[(size_t)srow * HDIM + (k - I)];
            short hi = f2bf(s);
            o[e] = (region == 2) ? f2bf(s - bf2f(hi)) : hi;
        }
    }
    *reinterpret_cast<int4*>(Wcat + (size_t)jp * KTOT + t * 8) =
        *reinterpret_cast<const int4*>(o);
}

struct PArgs {
    const short *xdhi, *xdlo, *xfhi, *xflo, *xffhi, *xfflo;
    const short *Wc0, *Wc1, *Wc2;
    const float *bc0, *bc1, *bc2;
    const float *headW;
    short *h0hi, *h1hi;
    float *parts;
    unsigned *flags;      // 4 groups x 64 u32 (monotonic step sequence)
};

// Counter-free flag barrier: block's arrival = one sc1 store of (s+1) to its
// slot; wave-0's 64 lanes poll all 64 slots (one coalesced 256B sweep) until
// all >= target. No RMW serialization, detection ~1 LLC round trip.
__device__ __forceinline__ void flag_barrier(unsigned* gflags, int slot,
                                             unsigned target, int tid)
{
    __syncthreads();      // per-wave vmcnt(0) drain: h sc1-stores at LLC
    if (tid < 64) {
        if (tid == 0) {
            asm volatile("global_store_dword %0, %1, off sc1"
                         :: "v"(gflags + slot), "v"(target) : "memory");
        }
        const unsigned* fp = gflags + tid;
        unsigned v;
        do {
            asm volatile("global_load_dword %0, %1, off sc1\n\ts_waitcnt vmcnt(0)"
                         : "=v"(v) : "v"(fp));
        } while (__ballot(v < target));
    }
    __syncthreads();
}

// One LSTM step. Wave w owns batch rows [bm*64+w*16,+16) x gate cols [bn*32,+32).
// A-frags via inline-asm loads: x first (plain), h after (sc1); vmcnt(16) lets
// the 12 x-only MFMAs run while h is in flight; vmcnt(0) before h MFMAs.
template<int I>
__device__ __forceinline__ void do_step(
    const short* __restrict__ Wl,
    float* __restrict__ c_l, float* __restrict__ hout_l,
    const float* __restrict__ bcl, const float* __restrict__ hwl,
    const short* __restrict__ xhi, const short* __restrict__ xlo,
    int T, int tloc,
    const short* __restrict__ hhi, short* __restrict__ hohi,
    float* __restrict__ parts, int seq_t, bool head,
    int bm, int bn, int tid)
{
    constexpr int XF = I / 32;
    constexpr int R0S = XF + 16;
    constexpr int KTOT = (2 * R0S + 2) * 32;
    const int w = tid >> 6, lane = tid & 63;
    const int l15 = lane & 15, lg = lane >> 4, gs = l15 & 3;
    const int brow = bm * 64 + w * 16 + l15;
    const int lg8 = lg * 8;

    short8 aphi[R0S], axlo[2];
    {
        const short* xbh = xhi + ((size_t)brow * T + tloc) * I + lg8;
        const short* xbl = xlo + ((size_t)brow * T + tloc) * I + lg8;
#pragma unroll
        for (int f = 0; f < XF; ++f) plain_load8(aphi[f], xbh + f * 32);
        plain_load8(axlo[0], xbl);
        if constexpr (XF == 2) plain_load8(axlo[1], xbl + 32);
        else                   axlo[1] = short8{0,0,0,0,0,0,0,0};
        const short* hb = hhi + ((size_t)brow << 9) + lg8;
#pragma unroll
        for (int f = 0; f < 16; ++f) agent_load8(aphi[XF + f], hb + f * 32);
    }

    f32x4 acc0 = {0.f,0.f,0.f,0.f}, acc1 = {0.f,0.f,0.f,0.f};
    const short* wb0 = Wl + l15 * KTOT;
    const short* wb1 = Wl + (16 + l15) * KTOT;
    const int x0 = l15 & 7, x1 = (16 + l15) & 7;

    auto BMFMA = [&](int ks, short8 a) {
        int g = ks * 4 + lg;
        short8 b0 = *reinterpret_cast<const short8*>(wb0 + ((g ^ x0) << 3));
        short8 b1 = *reinterpret_cast<const short8*>(wb1 + ((g ^ x1) << 3));
        acc0 = __builtin_amdgcn_mfma_f32_16x16x32_bf16(a, b0, acc0, 0, 0, 0);
        acc1 = __builtin_amdgcn_mfma_f32_16x16x32_bf16(a, b1, acc1, 0, 0, 0);
    };

    asm volatile("s_waitcnt vmcnt(16)" ::: "memory");   // x done, h in flight
    __builtin_amdgcn_sched_barrier(0);
#pragma unroll
    for (int f = 0; f < XF; ++f) BMFMA(f, aphi[f]);            // r0 x part
    BMFMA(R0S, axlo[0]);                                       // r1
    BMFMA(R0S + 1, axlo[1]);
#pragma unroll
    for (int f = 0; f < XF; ++f) BMFMA(R0S + 2 + f, aphi[f]);  // r2 x part
    asm volatile("s_waitcnt vmcnt(0)" ::: "memory");    // h ready
    __builtin_amdgcn_sched_barrier(0);
#pragma unroll
    for (int f = 0; f < 16; ++f) BMFMA(XF + f, aphi[XF + f]);            // r0 h
#pragma unroll
    for (int f = 0; f < 16; ++f) BMFMA(R0S + 2 + XF + f, aphi[XF + f]);  // r2 h

    // Epilogue: D row = lg*4+r (batch), col = l15 -> j'; 4-lane groups = i,f,g,o.
    float hp[4] = {0.f, 0.f, 0.f, 0.f};
#pragma unroll
    for (int nf = 0; nf < 2; ++nf) {
        float bias = bcl[nf * 16 + l15];
        int ul = nf * 4 + (l15 >> 2);
#pragma unroll
        for (int r = 0; r < 4; ++r) {
            float v = (nf ? acc1[r] : acc0[r]) + bias;
            float act = (gs == 2) ? fast_tanh(v) : fast_sigmoid(v);
            int base = lane & ~3;
            float ai = __shfl(act, base,     64);
            float af = __shfl(act, base | 1, 64);
            float ag = __shfl(act, base | 2, 64);
            float ao = __shfl(act, base | 3, 64);
            int bl = w * 16 + lg * 4 + r;
            int ci = bl * 8 + ul;
            float cn = af * c_l[ci] + ai * ag;
            float hn = ao * fast_tanh(cn);
            if (gs == 0) { c_l[ci] = cn; hout_l[ci] = hn; }
            if (head) {
                float p = (gs == 0) ? hn * hwl[ul] : 0.f;
                p += __shfl_xor(p, 4, 64);
                p += __shfl_xor(p, 8, 64);
                hp[r] += p;
            }
        }
    }
    if (head && l15 == 0) {
#pragma unroll
        for (int r = 0; r < 4; ++r) {
            int bg = bm * 64 + w * 16 + lg * 4 + r;
            parts[((size_t)bg * NSEQ + seq_t) * 64 + bn] = hp[r];
        }
    }
    __syncthreads();
    // h copy by wave 0: bf16-hi only, agent stores to the exchange buffer
    if (tid < 64) {
        short oh[8];
#pragma unroll
        for (int e = 0; e < 8; ++e) oh[e] = f2bf(hout_l[tid * 8 + e]);
        size_t off = ((size_t)(bm * 64 + tid) << 9) + bn * 8;
        agent_store16(hohi + off, *reinterpret_cast<const int4v*>(oh));
    }
}

__global__ __launch_bounds__(256, 1)
void lstm_persist(PArgs a)
{
    __shared__ short Wl[32 * 1216];       // 77824 B (enc layout; dec fits)
    __shared__ float c_l[512];
    __shared__ float hout_l[512];
    __shared__ float bcl[32];
    __shared__ float hwl[8];

    const int tid = threadIdx.x;
    const int bn = blockIdx.x & 63;
    const int bm = blockIdx.x >> 6;
    unsigned* gflags = a.flags + bm * 64;

    for (int i = tid; i < 512; i += 256) c_l[i] = 0.f;
    if (tid < 8) hwl[tid] = a.headW[bn * 8 + tid];

    for (int s = 0; s < 480; ++s) {
        const short *xhi, *xlo, *Wc;
        const float* bc;
        int T, tloc, I_;
        if (s < 336) {
            xhi = a.xdhi; xlo = a.xdlo; Wc = a.Wc0; bc = a.bc0;
            T = 336; tloc = s; I_ = 64;
        } else if (s < 432) {
            xhi = a.xfhi; xlo = a.xflo; Wc = a.Wc1; bc = a.bc1;
            T = 96; tloc = s - 336; I_ = 32;
        } else {
            xhi = a.xffhi; xlo = a.xfflo; Wc = a.Wc2; bc = a.bc2;
            T = 48; tloc = s - 432; I_ = 32;
        }
        if (s == 0 || s == 336 || s == 432) {
            const int KT = (I_ == 64) ? 1216 : 1152;
            const int GR8 = (I_ == 64) ? 19 : 18;     // granules/row / 8
            __syncthreads();
            int row = tid >> 3, g0 = tid & 7;
            const short* src = Wc + (size_t)(bn * 32 + row) * KT;
            for (int i2 = 0; i2 < GR8; ++i2) {
                int g = g0 + i2 * 8;
                *reinterpret_cast<int4*>(Wl + row * KT + ((g ^ (row & 7)) << 3)) =
                    *reinterpret_cast<const int4*>(src + g * 8);
            }
            if (tid < 32) bcl[tid] = bc[bn * 32 + tid];
            __syncthreads();
        }
        const int par = s & 1;
        const short* hhi = par ? a.h1hi : a.h0hi;
        short* hohi = par ? a.h0hi : a.h1hi;
        bool head = s >= 336;
        int seq_t = s - 336;
        if (I_ == 64)
            do_step<64>(Wl, c_l, hout_l, bcl, hwl, xhi, xlo, T, tloc,
                        hhi, hohi, a.parts, seq_t, head, bm, bn, tid);
        else
            do_step<32>(Wl, c_l, hout_l, bcl, hwl, xhi, xlo, T, tloc,
                        hhi, hohi, a.parts, seq_t, head, bm, bn, tid);
        flag_barrier(gflags, bn, (unsigned)(s + 1), tid);
    }
}

__global__ __launch_bounds__(256)
void head_finish_kernel(const float* __restrict__ partials,
                        const float* __restrict__ head_b,
                        float* __restrict__ out)
{
    int idx = blockIdx.x * 256 + threadIdx.x;   // b*144 + t
    if (idx >= BATCH * NSEQ) return;
    const float* p = partials + (size_t)idx * 64;
    float s = head_b[0];
#pragma unroll
    for (int i = 0; i < 64; ++i) s += p[i];
    out[idx] = s;
}

extern "C" void kernel_launch(void* const* d_in, const int* in_sizes, int n_in,
                              void* d_out, int out_size, void* d_ws, size_t ws_size,
                              hipStream_t stream) {
    const float* x_d      = (const float*)d_in[0];
    const float* x_f      = (const float*)d_in[1];
    const float* x_ff     = (const float*)d_in[2];
    const float* enc_Wih  = (const float*)d_in[3];
    const float* enc_Whh  = (const float*)d_in[4];
    const float* enc_bih  = (const float*)d_in[5];
    const float* enc_bhh  = (const float*)d_in[6];
    const float* decf_Wih = (const float*)d_in[7];
    const float* decf_Whh = (const float*)d_in[8];
    const float* decf_bih = (const float*)d_in[9];
    const float* decf_bhh = (const float*)d_in[10];
    const float* decff_Wih = (const float*)d_in[11];
    const float* decff_Whh = (const float*)d_in[12];
    const float* decff_bih = (const float*)d_in[13];
    const float* decff_bhh = (const float*)d_in[14];
    const float* head_W   = (const float*)d_in[15];
    const float* head_b   = (const float*)d_in[16];
    float* out = (float*)d_out;

    char* base = (char*)d_ws;
    short* h0hi  = (short*)(base + 0);            //   262144 B
    short* h1hi  = (short*)(base + 262144);       //   262144
    unsigned* flags = (unsigned*)(base + 524288); //     1024
    float* parts = (float*)(base + 525312);       //  9437184
    float* bcomb = (float*)(base + 9962496);      //    24576
    short* Wcat  = (short*)(base + 9987072);      // 14417920 (1216+1152+1152 x2048 x2B)
    short* xdhi  = (short*)(base + 24404992);     // 11010048
    short* xdlo  = (short*)(base + 35415040);     // 11010048
    short* xfhi  = (short*)(base + 46425088);     //  1572864
    short* xflo  = (short*)(base + 47997952);     //  1572864
    short* xffhi = (short*)(base + 49570816);     //   786432
    short* xfflo = (short*)(base + 50357248);     //   786432
    short* Wc1   = Wcat + (size_t)2048 * 1216;
    short* Wc2   = Wc1  + (size_t)2048 * 1152;

    // zero h0, h1, flags
    hipMemsetAsync(base, 0, 525312, stream);

    // input split-precision conversion
    xconv_kernel<<<dim3(5376), dim3(256), 0, stream>>>(x_d,  xdhi,  xdlo,  1376256);
    xconv_kernel<<<dim3(768),  dim3(256), 0, stream>>>(x_f,  xfhi,  xflo,  196608);
    xconv_kernel<<<dim3(384),  dim3(256), 0, stream>>>(x_ff, xffhi, xfflo, 98304);

    // weight prep
    wprep_kernel<64><<<dim3(2048), dim3(256), 0, stream>>>(
        enc_Wih, enc_Whh, enc_bih, enc_bhh, Wcat, bcomb);
    wprep_kernel<32><<<dim3(2048), dim3(256), 0, stream>>>(
        decf_Wih, decf_Whh, decf_bih, decf_bhh, Wc1, bcomb + 2048);
    wprep_kernel<32><<<dim3(2048), dim3(256), 0, stream>>>(
        decff_Wih, decff_Whh, decff_bih, decff_bhh, Wc2, bcomb + 4096);

    // persistent recurrence (one dispatch for all 480 steps)
    PArgs pa;
    pa.xdhi = xdhi; pa.xdlo = xdlo; pa.xfhi = xfhi; pa.xflo = xflo;
    pa.xffhi = xffhi; pa.xfflo = xfflo;
    pa.Wc0 = Wcat; pa.Wc1 = Wc1; pa.Wc2 = Wc2;
    pa.bc0 = bcomb; pa.bc1 = bcomb + 2048; pa.bc2 = bcomb + 4096;
    pa.headW = head_W;
    pa.h0hi = h0hi; pa.h1hi = h1hi;
    pa.parts = parts;
    pa.flags = flags;
    void* kargs[] = { &pa };
    hipError_t ce = hipLaunchCooperativeKernel((const void*)lstm_persist,
                                               dim3(256), dim3(256), kargs,
                                               0, stream);
    if (ce != hipSuccess) {
        lstm_persist<<<dim3(256), dim3(256), 0, stream>>>(pa);
    }

    head_finish_kernel<<<dim3((BATCH * NSEQ + 255) / 256), dim3(256), 0, stream>>>(
        parts, head_b, out);
}